// Round 6
// baseline (44.269 us; speedup 1.0000x reference)
//
#include <hip/hip_runtime.h>
#include <math.h>

// Directional Chamfer: sum_m min_n ||t_m - s_n||^2.
// q = 2 t.s - |s|^2 (maximize), d2 = |t|^2 - qmax.
// Main: v_pk_fma_f32 (2 scan pts/instr) + v_max3_f32. LDS pair-packed.
// Reduce: single kernel — 200-deep unrolled chunk-max + d2 + block sums +
// ticketed last-block final sum (2 dispatches total).

typedef float v2 __attribute__((ext_vector_type(2)));

#define TPT 8
#define BLK 256
#define MPB (TPT * BLK)   // 2048 templates per block
#define CHUNK 100         // scan points per chunk (200*100 = 20000 exactly)

__device__ __forceinline__ v2 pk_fma(v2 a, v2 b, v2 c) {
    v2 d;
    asm("v_pk_fma_f32 %0, %1, %2, %3" : "=v"(d) : "v"(a), "v"(b), "v"(c));
    return d;
}
__device__ __forceinline__ float max3(float a, float b, float c) {
    float d;
    asm("v_max3_f32 %0, %1, %2, %3" : "=v"(d) : "v"(a), "v"(b), "v"(c));
    return d;
}

__global__ void __launch_bounds__(BLK) chamfer_main(
    const float* __restrict__ scan, const float* __restrict__ tmpl,
    float* __restrict__ part, unsigned* __restrict__ counter, int M, int N) {
    __shared__ float4 lds4[(CHUNK + 1) / 2 * 2];
    float* ldsf = (float*)lds4;

    if (blockIdx.x == 0 && blockIdx.y == 0 && threadIdx.x == 0) *counter = 0u;

    int c = blockIdx.y;
    int j0 = c * CHUNK;
    int cnt = N - j0;
    if (cnt > CHUNK) cnt = CHUNK;

    for (int i = threadIdx.x; i < cnt; i += BLK) {
        float x = scan[3 * (j0 + i) + 0];
        float y = scan[3 * (j0 + i) + 1];
        float z = scan[3 * (j0 + i) + 2];
        float* bp = &ldsf[(i >> 1) * 8];
        int h = i & 1;
        bp[0 + h] = 2.f * x;
        bp[2 + h] = 2.f * y;
        bp[4 + h] = 2.f * z;
        bp[6 + h] = -(x * x + y * y + z * z);
    }
    if ((cnt & 1) && threadIdx.x == 0) {  // pad odd tail so hi half is inert
        float* bp = &ldsf[(cnt >> 1) * 8];
        bp[1] = 0.f; bp[3] = 0.f; bp[5] = 0.f; bp[7] = -INFINITY;
    }
    __syncthreads();

    int base = blockIdx.x * MPB + threadIdx.x;
    v2 txx[TPT], tyy[TPT], tzz[TPT];
    float q[TPT];
#pragma unroll
    for (int k = 0; k < TPT; ++k) {
        int m = base + k * BLK;
        float x = 0.f, y = 0.f, z = 0.f;
        if (m < M) {
            x = tmpl[3 * m + 0];
            y = tmpl[3 * m + 1];
            z = tmpl[3 * m + 2];
        }
        txx[k] = (v2){x, x};
        tyy[k] = (v2){y, y};
        tzz[k] = (v2){z, z};
        q[k] = -INFINITY;
    }

    int npair = (cnt + 1) >> 1;
#pragma unroll 2
    for (int p = 0; p < npair; ++p) {
        float4 a = lds4[2 * p + 0];  // broadcast read: {2x0,2x1,2y0,2y1}
        float4 b = lds4[2 * p + 1];  // {2z0,2z1,-n0,-n1}
        v2 xx = (v2){a.x, a.y};
        v2 yy = (v2){a.z, a.w};
        v2 zz = (v2){b.x, b.y};
        v2 ww = (v2){b.z, b.w};
#pragma unroll
        for (int k = 0; k < TPT; ++k) {
            v2 r = pk_fma(tzz[k], zz, ww);
            r = pk_fma(tyy[k], yy, r);
            r = pk_fma(txx[k], xx, r);
            q[k] = max3(q[k], r.x, r.y);
        }
    }

#pragma unroll
    for (int k = 0; k < TPT; ++k) {
        int m = base + k * BLK;
        if (m < M) part[(size_t)c * M + m] = q[k];
    }
}

// Fused reduce: per-template max over all NC chunks (unrolled independent
// loads), d2, fixed-order block sums, ticketed last-block final sum.
__global__ void __launch_bounds__(256) chamfer_reduce(
    const float* __restrict__ tmpl, const float* __restrict__ part,
    float* __restrict__ blockSums, unsigned* __restrict__ counter,
    float* __restrict__ out, int M, int NC, int nb) {
    int bx = blockIdx.x;
    int m = bx * 256 + threadIdx.x;
    float d2 = 0.f;
    if (m < M) {
        float q0 = -INFINITY, q1 = -INFINITY, q2 = -INFINITY, q3 = -INFINITY;
        int c = 0;
        for (; c + 3 < NC; c += 4) {
            float a = part[(size_t)(c + 0) * M + m];
            float b = part[(size_t)(c + 1) * M + m];
            float e = part[(size_t)(c + 2) * M + m];
            float f = part[(size_t)(c + 3) * M + m];
            q0 = fmaxf(q0, a);
            q1 = fmaxf(q1, b);
            q2 = fmaxf(q2, e);
            q3 = fmaxf(q3, f);
        }
        for (; c < NC; ++c) q0 = fmaxf(q0, part[(size_t)c * M + m]);
        float qmax = fmaxf(fmaxf(q0, q1), fmaxf(q2, q3));
        float x = tmpl[3 * m + 0];
        float y = tmpl[3 * m + 1];
        float z = tmpl[3 * m + 2];
        d2 = fmaf(x, x, fmaf(y, y, z * z)) - qmax;
        if (d2 < 0.f) d2 = 0.f;
    }
    for (int off = 32; off >= 1; off >>= 1) d2 += __shfl_down(d2, off, 64);
    __shared__ float wsum[4];
    __shared__ int islast;
    int lane = threadIdx.x & 63;
    int wid = threadIdx.x >> 6;
    if (lane == 0) wsum[wid] = d2;
    __syncthreads();
    if (threadIdx.x == 0) {
        float bs = wsum[0] + wsum[1] + wsum[2] + wsum[3];
        __hip_atomic_store(&blockSums[bx], bs, __ATOMIC_RELEASE,
                           __HIP_MEMORY_SCOPE_AGENT);
        unsigned t = __hip_atomic_fetch_add(counter, 1u, __ATOMIC_ACQ_REL,
                                            __HIP_MEMORY_SCOPE_AGENT);
        islast = (t == (unsigned)(nb - 1));
    }
    __syncthreads();
    if (islast) {
        float s = 0.f;
        for (int i = threadIdx.x; i < nb; i += 64)
            s += __hip_atomic_load(&blockSums[i], __ATOMIC_RELAXED,
                                   __HIP_MEMORY_SCOPE_AGENT);
        if (threadIdx.x < 64) {
            for (int off = 32; off >= 1; off >>= 1)
                s += __shfl_down(s, off, 64);
            if (threadIdx.x == 0) out[0] = s;
        }
    }
}

extern "C" void kernel_launch(void* const* d_in, const int* in_sizes, int n_in,
                              void* d_out, int out_size, void* d_ws,
                              size_t ws_size, hipStream_t stream) {
    const float* scan = (const float*)d_in[0];   // [N,3]
    const float* tmpl = (const float*)d_in[1];   // [M,3]
    int N = in_sizes[0] / 3;
    int M = in_sizes[1] / 3;
    float* out = (float*)d_out;

    int GX = (M + MPB - 1) / MPB;        // 5
    int NC = (N + CHUNK - 1) / CHUNK;    // 200
    int MB = (M + 255) / 256;            // 40

    char* ws = (char*)d_ws;
    unsigned* counter = (unsigned*)ws;                    // 4 B
    float* blockSums = (float*)(ws + 256);                // MB floats
    float* part = (float*)(ws + 4096);                    // NC*M floats

    dim3 grid(GX, NC);
    chamfer_main<<<grid, BLK, 0, stream>>>(scan, tmpl, part, counter, M, N);
    chamfer_reduce<<<MB, 256, 0, stream>>>(tmpl, part, blockSums, counter,
                                           out, M, NC, MB);
}